// Round 3
// baseline (471.201 us; speedup 1.0000x reference)
//
#include <hip/hip_runtime.h>
#include <hip/hip_bf16.h>

// WOQ int4-asym (tinygemm) linear: out[64,8192] = x @ dequant(w).T
// dequant: (q - 8)*scale + zp, groups of 128 along K.
//
// R5 = R4 with the compile fix (__builtin_bit_cast -> __builtin_memcpy on
// __hip_bfloat162). Design rationale (vs R3's 178us, floor ~41us):
//   1) grid 512 x 512thr (BN=16): 2 blocks/CU -> 4 waves/SIMD (R3 had 2).
//   2) unique weight ownership: wave = K-eighth, no duplication
//      (R3 re-fetched weights after unsynced wave drift -> ~512MB HBM).
//   3) explicit depth-2 weight prefetch; per-iter the only wait is on the
//      L2-hit x loads, HBM weight loads stay in flight ~2 iters (>900cyc).
//   4) packed bf16 convert via __float22bfloat162_rn.
// Zero workspace / no atomics / no memset: one kernel, LDS k-reduction.

#define OUT_F 8192
#define IN_F  8192
#define M_TOK 64
#define GROUP 128
#define BN    16
#define KWAVE 8
#define KR    (IN_F / KWAVE)    // 1024 k per wave
#define ITERS (KR / 32)         // 32

typedef short short8 __attribute__((ext_vector_type(8)));
typedef float f32x4  __attribute__((ext_vector_type(4)));
typedef unsigned u32x4 __attribute__((ext_vector_type(4)));

// pack two fp32 -> packed bf16 pair (RNE)
__device__ __forceinline__ unsigned pk(float lo, float hi) {
    __hip_bfloat162 h = __float22bfloat162_rn(float2{lo, hi});
    unsigned r;
    __builtin_memcpy(&r, &h, sizeof(r));
    return r;
}

__global__ __launch_bounds__(512, 4)
void woq_gemm(const float* __restrict__ x,
              const int*   __restrict__ qw,
              const float* __restrict__ sz,
              float*       __restrict__ outp) {
    // k-reduction: 8 wave-slots x 4 frags x 64 lanes x 16 B = 32 KB
    __shared__ f32x4 red[8 * 4 * 64];

    const int t    = threadIdx.x;
    const int lane = t & 63;
    const int wv   = t >> 6;        // 0..7 = k-eighth
    const int n0   = blockIdx.x * BN;

    const int nlo  = lane & 15;
    const int quad = lane >> 4;
    const int kq8  = quad << 3;

    const int n1 = n0 + nlo;                          // this lane's n column
    const int*   qr = qw + (size_t)n1 * IN_F;         // weight row
    const float* xr = x  + (size_t)nlo * IN_F;        // x row (frag mi adds mi*16 rows)
    const int kbase = wv * KR;

    f32x4 acc[4];
#pragma unroll
    for (int mi = 0; mi < 4; ++mi) acc[mi] = (f32x4){0.f, 0.f, 0.f, 0.f};

    // ---- depth-2 weight prefetch ----
    int4 wa0, wb0, wa1, wb1;
    {
        const int* p0 = qr + kbase + kq8;
        wa0 = *(const int4*)(p0);
        wb0 = *(const int4*)(p0 + 4);
        const int* p1 = qr + kbase + 32 + kq8;
        wa1 = *(const int4*)(p1);
        wb1 = *(const int4*)(p1 + 4);
    }

    float s1 = 0.f, c1 = 0.f;

#pragma unroll 4
    for (int it = 0; it < ITERS; ++it) {
        if ((it & 3) == 0) {   // new group of 128 (uniform branch)
            const int gg = (kbase + it * 32) >> 7;
            const float2 p = *(const float2*)(sz + ((size_t)gg * OUT_F + n1) * 2);
            s1 = p.x;
            c1 = fmaf(-8.f, p.x, p.y);
        }

        const int kk = kbase + it * 32;

        // 1) x loads first (L2-hit) — the per-iter wait lands on these,
        //    leaving the weight prefetches below still in flight.
        float4 xv[4][2];
#pragma unroll
        for (int mi = 0; mi < 4; ++mi) {
            const float4* xp = (const float4*)(xr + (size_t)mi * 16 * IN_F + kk + kq8);
            xv[mi][0] = xp[0];
            xv[mi][1] = xp[1];
        }

        // 2) prefetch weights for it+2 (HBM-critical stream)
        int4 wa2, wb2;
        {
            const int itn = (it + 2 < ITERS) ? it + 2 : ITERS - 1;
            const int* pn = qr + kbase + itn * 32 + kq8;
            wa2 = *(const int4*)(pn);
            wb2 = *(const int4*)(pn + 4);
        }

        // 3) pack A (waits x only)
        short8 a[4];
#pragma unroll
        for (int mi = 0; mi < 4; ++mi) {
            u32x4 ai;
            ai.x = pk(xv[mi][0].x, xv[mi][0].y);
            ai.y = pk(xv[mi][0].z, xv[mi][0].w);
            ai.z = pk(xv[mi][1].x, xv[mi][1].y);
            ai.w = pk(xv[mi][1].z, xv[mi][1].w);
            a[mi] = __builtin_bit_cast(short8, ai);
        }

        // 4) dequant B from w(it) — loaded 2 iters ago, already arrived
        u32x4 bi;
        bi.x = pk(fmaf((float)wa0.x, s1, c1), fmaf((float)wa0.y, s1, c1));
        bi.y = pk(fmaf((float)wa0.z, s1, c1), fmaf((float)wa0.w, s1, c1));
        bi.z = pk(fmaf((float)wb0.x, s1, c1), fmaf((float)wb0.y, s1, c1));
        bi.w = pk(fmaf((float)wb0.z, s1, c1), fmaf((float)wb0.w, s1, c1));
        const short8 b = __builtin_bit_cast(short8, bi);

#pragma unroll
        for (int mi = 0; mi < 4; ++mi)
            acc[mi] = __builtin_amdgcn_mfma_f32_16x16x32_bf16(a[mi], b, acc[mi], 0, 0, 0);

        // rotate prefetch pipeline
        wa0 = wa1; wb0 = wb1;
        wa1 = wa2; wb1 = wb2;
    }

    // ---- cross-wave k-reduction via LDS ----
#pragma unroll
    for (int mi = 0; mi < 4; ++mi)
        red[(wv * 4 + mi) * 64 + lane] = acc[mi];
    __syncthreads();

    if (wv < 4) {               // wave w sums fragment mi=w across 8 slots
        f32x4 s = red[(0 * 4 + wv) * 64 + lane];
#pragma unroll
        for (int sl = 1; sl < 8; ++sl)
            s += red[(sl * 4 + wv) * 64 + lane];
        // C/D: col = lane&15 (n), row = quad*4 + r (m within frag)
#pragma unroll
        for (int r = 0; r < 4; ++r) {
            const int m = wv * 16 + quad * 4 + r;
            outp[(size_t)m * OUT_F + n0 + nlo] = s[r];
        }
    }
}

extern "C" void kernel_launch(void* const* d_in, const int* in_sizes, int n_in,
                              void* d_out, int out_size, void* d_ws, size_t ws_size,
                              hipStream_t stream) {
    const float* x  = (const float*)d_in[0];
    const int*   qw = (const int*)d_in[1];
    const float* sz = (const float*)d_in[2];
    woq_gemm<<<dim3(OUT_F / BN), 512, 0, stream>>>(x, qw, sz, (float*)d_out);
}

// Round 4
// 394.594 us; speedup vs baseline: 1.1941x; 1.1941x over previous
//
#include <hip/hip_runtime.h>
#include <hip/hip_bf16.h>

// WOQ int4-asym (tinygemm) linear: out[64,8192] = x @ dequant(w).T
// dequant: (q - 8)*scale + zp, groups of 128 along K.
//
// R6: back to the proven LDS-staged-A structure (R1 ~65us) and fix R5's
// fatal flaw: A-frags from global x put every iteration's wait on vmcnt,
// and ordered-vmcnt waits drained the weight prefetches (212us, 9% HBM,
// VGPR=52 collapsed pipeline). With A in LDS, a-frag reads wait on
// lgkmcnt only -> the HBM weight stream is the sole vmcnt consumer and
// the compiler keeps ~8KB/wave of weight loads in flight per group.
// Upgrades over R1:
//   - double-buffered x stages, ONE barrier per 128-k group (R1 had 2,
//     each a full vmcnt drain between stage and compute);
//   - T14 order: issue x loads for g+1 -> compute g -> pack+ds_write;
//   - KSPLIT 16->8, BN=64: grid 128x8=1024 blocks, 4 blocks/CU,
//     16 waves/CU; unsynced neighbor blocks cover barrier drains;
//   - zero-ws epilogue: f32 atomicAdd (4.2M lane-ops, ~16MB) onto a
//     pre-zeroed output (tiny kernel). No reduce pass. The 1-GiB d_ws
//     poison fill runs unconditionally (R3/R5 evidence), so ws buys
//     nothing; atomics were never the R1 bottleneck (the fills were).

#define OUT_F 8192
#define IN_F  8192
#define M_TOK 64
#define GROUP 128
#define BN    64
#define KSPLIT 8
#define KR    (IN_F / KSPLIT)   // 1024 k per block
#define GROUPS (KR / GROUP)     // 8

typedef short short8 __attribute__((ext_vector_type(8)));
typedef float f32x4  __attribute__((ext_vector_type(4)));
typedef unsigned u32x4 __attribute__((ext_vector_type(4)));

// pack two fp32 -> packed bf16 pair (RNE, v_cvt_pk_bf16_f32)
__device__ __forceinline__ unsigned pk(float lo, float hi) {
    __hip_bfloat162 h = __float22bfloat162_rn(float2{lo, hi});
    unsigned r;
    __builtin_memcpy(&r, &h, sizeof(r));
    return r;
}

__global__ void zero_out(float* __restrict__ p) {
    const int i = (blockIdx.x * 256 + threadIdx.x) * 4;
    *(float4*)(p + i) = float4{0.f, 0.f, 0.f, 0.f};
}

__global__ __launch_bounds__(256, 4)
void woq_gemm(const float* __restrict__ x,
              const int*   __restrict__ qw,
              const float* __restrict__ sz,
              float*       __restrict__ outp) {
    // two 16 KB bf16 x-tiles: buf[b][slot*4..+4], slot=(chunk)*64+lane,
    // chunk = ks*4+mi; lane l holds x[mi*16+(l&15)][ks*32+(l>>4)*8 ..+8]
    __shared__ int lds_x[2][1024 * 4];

    const int t    = threadIdx.x;
    const int lane = t & 63;
    const int wv   = t >> 6;          // wave 0..3 -> n-offset wv*16
    const int n0   = blockIdx.x * BN;
    const int k0   = blockIdx.y * KR;

    const int nlo  = lane & 15;
    const int quad = lane >> 4;
    const int kq8  = quad << 3;

    const int n1 = n0 + wv * 16 + nlo;           // this lane's n column
    const int* qr = qw + (size_t)n1 * IN_F;      // weight row

    f32x4 acc[4];
#pragma unroll
    for (int mi = 0; mi < 4; ++mi) acc[mi] = (f32x4){0.f, 0.f, 0.f, 0.f};

    float4 xs[8];   // staging registers for the next group's x tile

    // ---- prologue: load + store stage for g=0 ----
#pragma unroll
    for (int i = 0; i < 4; ++i) {
        const int slot  = t + 256 * i;
        const int chunk = slot >> 6;
        const int l     = slot & 63;
        const int m     = ((chunk & 3) << 4) + (l & 15);
        const int kk    = ((chunk >> 2) << 5) + ((l >> 4) << 3);
        const float4* p = (const float4*)(x + (size_t)m * IN_F + k0 + kk);
        xs[2 * i]     = p[0];
        xs[2 * i + 1] = p[1];
    }
#pragma unroll
    for (int i = 0; i < 4; ++i) {
        const int slot = t + 256 * i;
        u32x4 bv;
        bv.x = pk(xs[2 * i].x,     xs[2 * i].y);
        bv.y = pk(xs[2 * i].z,     xs[2 * i].w);
        bv.z = pk(xs[2 * i + 1].x, xs[2 * i + 1].y);
        bv.w = pk(xs[2 * i + 1].z, xs[2 * i + 1].w);
        *(u32x4*)&lds_x[0][slot * 4] = bv;
    }
    __syncthreads();

    for (int g = 0; g < GROUPS; ++g) {
        const int kg = k0 + g * GROUP;

        // 1) issue global x loads for group g+1 (latency hidden by compute)
        if (g + 1 < GROUPS) {
#pragma unroll
            for (int i = 0; i < 4; ++i) {
                const int slot  = t + 256 * i;
                const int chunk = slot >> 6;
                const int l     = slot & 63;
                const int m     = ((chunk & 3) << 4) + (l & 15);
                const int kk    = ((chunk >> 2) << 5) + ((l >> 4) << 3);
                const float4* p = (const float4*)(x + (size_t)m * IN_F + kg + GROUP + kk);
                xs[2 * i]     = p[0];
                xs[2 * i + 1] = p[1];
            }
        }

        // 2) compute group g from lds buffer g&1
        const int gg = kg >> 7;   // global group index for scales
        const float2 ps = *(const float2*)(sz + ((size_t)gg * OUT_F + n1) * 2);
        const float s1 = ps.x, c1 = fmaf(-8.f, ps.x, ps.y);
        const int* bufp = lds_x[g & 1];

#pragma unroll
        for (int ks = 0; ks < 4; ++ks) {
            // weight stream: the HBM-critical loads (8 KB/wave/group in flight)
            const int* qp = qr + kg + ks * 32 + kq8;
            const int4 qa = *(const int4*)(qp);
            const int4 qb = *(const int4*)(qp + 4);

            short8 a[4];
#pragma unroll
            for (int mi = 0; mi < 4; ++mi)
                a[mi] = *(const short8*)&bufp[((ks * 4 + mi) * 64 + lane) * 4];

            u32x4 bi;
            bi.x = pk(fmaf((float)qa.x, s1, c1), fmaf((float)qa.y, s1, c1));
            bi.y = pk(fmaf((float)qa.z, s1, c1), fmaf((float)qa.w, s1, c1));
            bi.z = pk(fmaf((float)qb.x, s1, c1), fmaf((float)qb.y, s1, c1));
            bi.w = pk(fmaf((float)qb.z, s1, c1), fmaf((float)qb.w, s1, c1));
            const short8 b = __builtin_bit_cast(short8, bi);

#pragma unroll
            for (int mi = 0; mi < 4; ++mi)
                acc[mi] = __builtin_amdgcn_mfma_f32_16x16x32_bf16(a[mi], b, acc[mi], 0, 0, 0);
        }

        // 3) pack + write stage for g+1 into the other buffer
        if (g + 1 < GROUPS) {
            int* dstb = lds_x[(g + 1) & 1];
#pragma unroll
            for (int i = 0; i < 4; ++i) {
                const int slot = t + 256 * i;
                u32x4 bv;
                bv.x = pk(xs[2 * i].x,     xs[2 * i].y);
                bv.y = pk(xs[2 * i].z,     xs[2 * i].w);
                bv.z = pk(xs[2 * i + 1].x, xs[2 * i + 1].y);
                bv.w = pk(xs[2 * i + 1].z, xs[2 * i + 1].w);
                *(u32x4*)&dstb[slot * 4] = bv;
            }
            __syncthreads();   // one barrier per group
        }
    }

    // ---- epilogue: atomic accumulate into pre-zeroed output ----
    // C/D layout: col = lane&15 (n), row = quad*4 + r (m within frag)
#pragma unroll
    for (int mi = 0; mi < 4; ++mi) {
#pragma unroll
        for (int r = 0; r < 4; ++r) {
            const int m = mi * 16 + quad * 4 + r;
            atomicAdd(outp + (size_t)m * OUT_F + n1, acc[mi][r]);
        }
    }
}

extern "C" void kernel_launch(void* const* d_in, const int* in_sizes, int n_in,
                              void* d_out, int out_size, void* d_ws, size_t ws_size,
                              hipStream_t stream) {
    const float* x  = (const float*)d_in[0];
    const int*   qw = (const int*)d_in[1];
    const float* sz = (const float*)d_in[2];
    float* out = (float*)d_out;

    zero_out<<<dim3((M_TOK * OUT_F) / (256 * 4)), 256, 0, stream>>>(out);
    woq_gemm<<<dim3(OUT_F / BN, KSPLIT), 256, 0, stream>>>(x, qw, sz, out);
}

// Round 5
// 376.258 us; speedup vs baseline: 1.2523x; 1.0487x over previous
//
#include <hip/hip_runtime.h>
#include <hip/hip_bf16.h>

// WOQ int4-asym (tinygemm) linear: out[64,8192] = x @ dequant(w).T
// dequant: (q - 8)*scale + zp, groups of 128 along K.
//
// R7: attack the persistent ~2 TB/s weight-stream wall (R1/R6 both ~125us
// vs 41us floor; VALUBusy 9%, MfmaUtil 2% => nothing on-chip busy).
// Theory: direct-to-consuming-lane weight loads fragment DRAM access into
// ~65K concurrent 128B-granule row streams -> HBM row-buffer thrash.
// Fix: COALESCED weight staging. Each wave staging instruction reads 1 KB
// linear (two full 512B row-chunks); weights are dequanted to bf16 during
// staging and placed in an XOR-swizzled LDS tile; compute phase is pure
// LDS+MFMA (lgkm-only, keeping R5's vmcnt-entanglement fix).
//   geometry: BN=64, KSPLIT=4 (KR=2048, 16 groups of 128), 512thr =
//   8 waves = 4 n-subtiles x 2 k-halves; LDS 64KB (x dbuf 32K + w dbuf
//   32K) -> 2 blocks/CU, 16 waves/CU; grid 128x4=512 = exactly 2/CU.
//   One barrier/group, T14 order: issue loads g+1 -> compute g ->
//   dequant+ds_write -> barrier.
// Epilogue: kh-pair LDS reduce, then 2.1M atomicAdd (half of R6) onto
// pre-zeroed output. Zero workspace (1-GiB ws poison is unconditional).

#define OUT_F 8192
#define IN_F  8192
#define M_TOK 64
#define GROUP 128
#define BN    64
#define KSPLIT 4
#define KR    (IN_F / KSPLIT)   // 2048 k per block
#define GROUPS (KR / GROUP)     // 16

typedef short short8 __attribute__((ext_vector_type(8)));
typedef float f32x4  __attribute__((ext_vector_type(4)));

// pack two fp32 -> packed bf16 pair (RNE, v_cvt_pk_bf16_f32)
__device__ __forceinline__ unsigned pk(float lo, float hi) {
    __hip_bfloat162 h = __float22bfloat162_rn(float2{lo, hi});
    unsigned r;
    __builtin_memcpy(&r, &h, sizeof(r));
    return r;
}

__global__ void zero_out(float* __restrict__ p) {
    const int i = (blockIdx.x * 256 + threadIdx.x) * 4;
    *(float4*)(p + i) = float4{0.f, 0.f, 0.f, 0.f};
}

__global__ __launch_bounds__(512, 4)
void woq_gemm(const float* __restrict__ x,
              const int*   __restrict__ qw,
              const float* __restrict__ sz,
              float*       __restrict__ outp) {
    // x tiles (bf16, MFMA frag order, dbuf): 2 x 16 KB
    //   slot = (ks*4+mi)*64 + lane; lane l holds x[mi*16+(l&15)][ks*32+(l>>4)*8..+8]
    // w tiles (bf16 [64 rows][128 k], XOR-swizzled, dbuf): 2 x 16 KB
    __shared__ int lds_x[2][4096];
    __shared__ int lds_w[2][4096];

    const int t    = threadIdx.x;       // 0..511
    const int lane = t & 63;
    const int wv   = t >> 6;            // 0..7
    const int wn   = wv & 3;            // n subtile (16 cols)
    const int kh   = wv >> 2;           // k half of each 128-group
    const int n0   = blockIdx.x * BN;
    const int k0   = blockIdx.y * KR;

    const int nlo  = lane & 15;
    const int quad = lane >> 4;
    const int row  = wn * 16 + nlo;     // tile row (n) this lane consumes
    const int n1   = n0 + row;

    // staging identities: chunk c = i*512 + t; row = c>>5 = i*16+tr; 16B col = kc
    const int tr = t >> 5;              // 0..15
    const int kc = t & 31;              // 0..31

    f32x4 acc[4];
#pragma unroll
    for (int mi = 0; mi < 4; ++mi) acc[mi] = (f32x4){0.f, 0.f, 0.f, 0.f};

    int4   wq[4];    // staged weights (4 rows, 16 B each, contiguous-in-row)
    float2 sc[4];    // scales for those rows
    float4 xs[4];    // staged x (2 slots x 32 B)

    auto stage_load = [&](int g) {
        const int kg = k0 + g * GROUP;
        // weights: per instr i, wave reads two full 512B row-chunks linearly
#pragma unroll
        for (int i = 0; i < 4; ++i) {
            const int r = i * 16 + tr;
            wq[i] = *(const int4*)(qw + (size_t)(n0 + r) * IN_F + kg + kc * 4);
        }
        const int gg = kg >> 7;
#pragma unroll
        for (int i = 0; i < 4; ++i) {
            const int r = i * 16 + tr;
            sc[i] = *(const float2*)(sz + ((size_t)gg * OUT_F + n0 + r) * 2);
        }
        // x tile (L2-resident)
#pragma unroll
        for (int j = 0; j < 2; ++j) {
            const int slot  = t + 512 * j;
            const int chunk = slot >> 6;
            const int l     = slot & 63;
            const int m     = ((chunk & 3) << 4) + (l & 15);
            const int kk    = ((chunk >> 2) << 5) + ((l >> 4) << 3);
            const float4* p = (const float4*)(x + (size_t)m * IN_F + kg + kk);
            xs[2 * j]     = p[0];
            xs[2 * j + 1] = p[1];
        }
    };

    auto stage_write = [&](int buf) {
        int* wb = lds_w[buf];
#pragma unroll
        for (int i = 0; i < 4; ++i) {
            const int r = i * 16 + tr;
            const float s = sc[i].x;
            const float c = fmaf(-8.f, sc[i].x, sc[i].y);
            int2 v;
            v.x = (int)pk(fmaf((float)wq[i].x, s, c), fmaf((float)wq[i].y, s, c));
            v.y = (int)pk(fmaf((float)wq[i].z, s, c), fmaf((float)wq[i].w, s, c));
            const int idx = (r * 64 + kc * 2) ^ ((r & 7) << 2);   // XOR swizzle
            *(int2*)&wb[idx] = v;
        }
        int* xb = lds_x[buf];
#pragma unroll
        for (int j = 0; j < 2; ++j) {
            const int slot = t + 512 * j;
            int4 bv;
            bv.x = (int)pk(xs[2 * j].x,     xs[2 * j].y);
            bv.y = (int)pk(xs[2 * j].z,     xs[2 * j].w);
            bv.z = (int)pk(xs[2 * j + 1].x, xs[2 * j + 1].y);
            bv.w = (int)pk(xs[2 * j + 1].z, xs[2 * j + 1].w);
            *(int4*)&xb[slot * 4] = bv;
        }
    };

    // prologue: stage group 0
    stage_load(0);
    stage_write(0);
    __syncthreads();

    for (int g = 0; g < GROUPS; ++g) {
        if (g + 1 < GROUPS) stage_load(g + 1);   // global loads fly over compute

        // compute group g: pure LDS + MFMA (no vmcnt dependence)
        const int* xb = lds_x[g & 1];
        const int* wb = lds_w[g & 1];
#pragma unroll
        for (int s = 0; s < 2; ++s) {
            const int ks = kh * 2 + s;
            const int bidx = (row * 64 + ks * 16 + quad * 4) ^ ((row & 7) << 2);
            const short8 b = *(const short8*)&wb[bidx];
            short8 a[4];
#pragma unroll
            for (int mi = 0; mi < 4; ++mi)
                a[mi] = *(const short8*)&xb[((ks * 4 + mi) * 64 + lane) * 4];
#pragma unroll
            for (int mi = 0; mi < 4; ++mi)
                acc[mi] = __builtin_amdgcn_mfma_f32_16x16x32_bf16(a[mi], b, acc[mi], 0, 0, 0);
        }

        if (g + 1 < GROUPS) {
            stage_write((g + 1) & 1);            // waits vmcnt, writes other buf
            __syncthreads();                     // one barrier per group
        }
    }

    // ---- epilogue: kh-pair reduce via LDS, then atomics ----
    __syncthreads();
    f32x4* redp = (f32x4*)&lds_x[0][0];          // 16 KB scratch (safe: last
    if (kh == 1) {                               // compute used lds_x[1])
#pragma unroll
        for (int mi = 0; mi < 4; ++mi)
            redp[(wn * 4 + mi) * 64 + lane] = acc[mi];
    }
    __syncthreads();
    if (kh == 0) {
#pragma unroll
        for (int mi = 0; mi < 4; ++mi)
            acc[mi] += redp[(wn * 4 + mi) * 64 + lane];
        // C/D layout: col = lane&15 (n), row = quad*4 + r (m within frag)
#pragma unroll
        for (int mi = 0; mi < 4; ++mi)
#pragma unroll
            for (int r = 0; r < 4; ++r)
                atomicAdd(outp + (size_t)(mi * 16 + quad * 4 + r) * OUT_F + n1, acc[mi][r]);
    }
}

extern "C" void kernel_launch(void* const* d_in, const int* in_sizes, int n_in,
                              void* d_out, int out_size, void* d_ws, size_t ws_size,
                              hipStream_t stream) {
    const float* x  = (const float*)d_in[0];
    const int*   qw = (const int*)d_in[1];
    const float* sz = (const float*)d_in[2];
    float* out = (float*)d_out;

    zero_out<<<dim3((M_TOK * OUT_F) / (256 * 4)), 256, 0, stream>>>(out);
    woq_gemm<<<dim3(OUT_F / BN, KSPLIT), 512, 0, stream>>>(x, qw, sz, out);
}